// Round 5
// baseline (351.786 us; speedup 1.0000x reference)
//
#include <hip/hip_runtime.h>
#include <hip/hip_bf16.h>

#define B_    2
#define C_    64
#define T_    1000
#define NF_   257
#define F_    64
#define H_    128
#define NFP_  288   // padded freq dim (rows zero-filled for k>=NF_)

typedef __bf16  bfv8  __attribute__((ext_vector_type(8)));
typedef float   f32x4 __attribute__((ext_vector_type(4)));
typedef short   s16x8 __attribute__((ext_vector_type(8)));

#define GLOBAL_AS __attribute__((address_space(1)))
#define SHARED_AS __attribute__((address_space(3)))

static __device__ __forceinline__ short f2bf(float f) {
  __hip_bfloat16 h = __float2bfloat16(f);
  return *reinterpret_cast<short*>(&h);
}
static __device__ __forceinline__ float bf2f(short s) {
  __hip_bfloat16 h = *reinterpret_cast<__hip_bfloat16*>(&s);
  return __bfloat162float(h);
}

static __device__ __forceinline__ void gload_lds16(const void* g, void* l) {
  __builtin_amdgcn_global_load_lds((const GLOBAL_AS void*)g, (SHARED_AS void*)l, 16, 0, 0);
}

// ---------------- x pre-pass: x[b,c,t,k] fp32 -> xT[b,t,k,c] bf16 (k zero-filled to NFP_)
// One block per (b,t). Each x row (257 floats, 1028 B) read as a contiguous span:
// <=3 scalar prefix to reach 16-B alignment, then lane-striped float4, <=3 scalar tail.
// LDS [64][268] bf16 (odd-word stride); write side emits 4-KB contiguous chunks.
__global__ __launch_bounds__(256) void xprep_kernel(const float* __restrict__ x,
                                                    short* __restrict__ xT) {
  __shared__ short Ls[64][268];
  const int t = blockIdx.x;
  const int b = blockIdx.y;
  const int wave = threadIdx.x >> 6;
  const int lane = threadIdx.x & 63;
#pragma unroll
  for (int r = 0; r < 16; ++r) {
    const int c = wave * 16 + r;
    const size_t off = (((size_t)(b * C_ + c)) * T_ + t) * NF_;
    const float* row = x + off;
    const int pre = (int)((4 - (off & 3)) & 3);
    const int nv  = (NF_ - pre) >> 2;
    const int rem = NF_ - pre - 4 * nv;
    if (lane < pre) Ls[c][lane] = f2bf(row[lane]);
    if (lane < nv) {
      f32x4 v4 = *reinterpret_cast<const f32x4*>(row + pre + 4 * lane);
#pragma unroll
      for (int u = 0; u < 4; ++u) Ls[c][pre + 4 * lane + u] = f2bf(v4[u]);
    }
    if (lane < rem) Ls[c][pre + 4 * nv + lane] = f2bf(row[pre + 4 * nv + lane]);
  }
  __syncthreads();
  {
    const int q  = threadIdx.x & 7;
    const int c0 = q * 8;
    short* obase = &xT[((size_t)(b * T_ + t)) * NFP_ * C_];
#pragma unroll
    for (int it = 0; it < 9; ++it) {
      int k = it * 32 + (threadIdx.x >> 3);
      s16x8 v;
      if (k < NF_) {
#pragma unroll
        for (int u = 0; u < 8; ++u) {
          int ue = (u + q) & 7;                 // rotation: spreads LDS read banks
          v[ue] = Ls[c0 + ue][k];
        }
      } else {
#pragma unroll
        for (int u = 0; u < 8; ++u) v[u] = 0;   // bf16 +0.0
      }
      *reinterpret_cast<s16x8*>(&obase[(size_t)k * C_ + c0]) = v;
    }
  }
}

// ---------------- W pre-pass: W[f,h,c,j] fp32 -> Wp[f,h,j,c] bf16 (j padded), width detect
__global__ __launch_bounds__(256) void wprep_kernel(const float* __restrict__ W,
                                                    short* __restrict__ Wp,
                                                    int* __restrict__ wwidth,
                                                    int jmax, int JPAD) {
  extern __shared__ short Lw[];
  __shared__ int smax;
  const int f  = blockIdx.x >> 4;
  const int h8 = (blockIdx.x & 15) * 8;
  const int tid = threadIdx.x;
  if (tid == 0) smax = 0;
  __syncthreads();
  const int chunk = 8 * C_ * jmax;
  const float* src = W + ((size_t)(f * H_ + h8)) * C_ * jmax;
  int lm = -1;
  for (int o = tid; o < chunk; o += 256) {
    float v = src[o];
    Lw[o] = f2bf(v);
    if (v != 0.0f) { int j = o % jmax; if (j > lm) lm = j; }
  }
  atomicMax(&smax, lm + 1);
  __syncthreads();
  if (tid == 0) atomicMax(&wwidth[f], smax);
  const int KP = C_ * JPAD;
  const int nv = 8 * JPAD * 8;
  for (int id = tid; id < nv; id += 256) {
    int c0 = (id & 7) * 8;
    int j  = (id >> 3) % JPAD;
    int h  = (id >> 3) / JPAD;
    s16x8 v;
    if (j < jmax) {
#pragma unroll
      for (int u = 0; u < 8; ++u) v[u] = Lw[h * C_ * jmax + (c0 + u) * jmax + j];
    } else {
      short z = 0;
#pragma unroll
      for (int u = 0; u < 8; ++u) v[u] = z;
    }
    *reinterpret_cast<s16x8*>(&Wp[((size_t)(f * H_ + h8 + h)) * KP + j * C_ + c0]) = v;
  }
}

// ---------------- batched gather-GEMM, 2-deep dbuf pipeline + counted vmcnt + XOR swizzle
// tile 128(t) x 128(h), BK=64 (one j slice), 4 waves of 64x64, mfma 16x16x32 bf16
__global__ __launch_bounds__(256) void gemm_kernel(const short* __restrict__ xT,
                                                   const short* __restrict__ Wp,
                                                   const int* __restrict__ idx,
                                                   const int* __restrict__ wwidth,
                                                   short* __restrict__ tmp,
                                                   int jmax, int JPAD) {
  __shared__ short As[2][128 * 64];
  __shared__ short Ws[2][128 * 64];
  const int id = blockIdx.x;                 // 0..1023
  const int sw = (id & 7) * 128 + (id >> 3); // bijective XCD swizzle (1024%8==0)
  const int f  = sw & 63;
  const int tb = sw >> 6;
  const int tt = tb & 7;
  const int b  = tb >> 3;
  const int t0 = tt * 128;
  const int tid  = threadIdx.x;
  const int wave = tid >> 6;
  const int lane = tid & 63;
  const int wm = wave >> 1, wn = wave & 1;
  const int start = idx[f * jmax];
  const int KP = C_ * JPAD;
  int wf = wwidth[f];
  if (wf > JPAD) wf = JPAD;

  const int lrow = lane >> 3;                     // == absolute_row & 7
  const int lsw  = ((lane & 7) ^ lrow) * 8;       // pre-swizzled global col (shorts)
  const int l7   = lane & 7;                      // == read row & 7

  f32x4 acc[4][4] = {};

#define STAGE(J, BSEL)                                                              \
  {                                                                                 \
    _Pragma("unroll")                                                               \
    for (int i = 0; i < 4; ++i) {                                                   \
      int tc = t0 + wave * 32 + i * 8 + lrow; if (tc >= T_) tc = T_ - 1;            \
      gload_lds16(&xT[(((size_t)(b * T_ + tc)) * NFP_ + (start + (J))) * C_ + lsw], \
                  &As[BSEL][(wave * 32 + i * 8) * 64]);                             \
    }                                                                               \
    _Pragma("unroll")                                                               \
    for (int i = 0; i < 4; ++i) {                                                   \
      int h = wave * 32 + i * 8 + lrow;                                             \
      gload_lds16(&Wp[((size_t)(f * H_ + h)) * KP + (J) * 64 + lsw],                \
                  &Ws[BSEL][(wave * 32 + i * 8) * 64]);                             \
    }                                                                               \
  }

  if (wf > 0) STAGE(0, 0);
  if (wf > 1) STAGE(1, 1);
  asm volatile("" ::: "memory");
  __builtin_amdgcn_sched_barrier(0);

  for (int j = 0; j < wf; ++j) {
    const int cur = j & 1;
    if (j + 1 < wf) asm volatile("s_waitcnt vmcnt(8)" ::: "memory");
    else            asm volatile("s_waitcnt vmcnt(0)" ::: "memory");
    __builtin_amdgcn_sched_barrier(0);
    asm volatile("s_barrier" ::: "memory");
    __builtin_amdgcn_sched_barrier(0);

#pragma unroll
    for (int ks = 0; ks < 2; ++ks) {
      bfv8 a[4], w[4];
#pragma unroll
      for (int mi = 0; mi < 4; ++mi) {
        int rA = wm * 64 + mi * 16 + (lane & 15);          // rA&7 == l7
        int sA = ((ks * 4 + (lane >> 4)) ^ l7) * 8;        // swizzled read slot
        a[mi] = *reinterpret_cast<const bfv8*>(&As[cur][rA * 64 + sA]);
      }
#pragma unroll
      for (int ni = 0; ni < 4; ++ni) {
        int rB = wn * 64 + ni * 16 + (lane & 15);
        int sB = ((ks * 4 + (lane >> 4)) ^ l7) * 8;
        w[ni] = *reinterpret_cast<const bfv8*>(&Ws[cur][rB * 64 + sB]);
      }
      __builtin_amdgcn_s_setprio(1);
#pragma unroll
      for (int mi = 0; mi < 4; ++mi)
#pragma unroll
        for (int ni = 0; ni < 4; ++ni)
          acc[mi][ni] = __builtin_amdgcn_mfma_f32_16x16x32_bf16(a[mi], w[ni], acc[mi][ni], 0, 0, 0);
      __builtin_amdgcn_s_setprio(0);
    }

    __builtin_amdgcn_sched_barrier(0);
    asm volatile("s_barrier" ::: "memory");   // all waves done reading buf[cur]
    __builtin_amdgcn_sched_barrier(0);
    if (j + 2 < wf) STAGE(j + 2, cur);        // overwrite cur for j+2
    asm volatile("" ::: "memory");
  }
#undef STAGE

  // epilogue: C/D layout col=lane&15 (h), row=(lane>>4)*4+q (t); store bf16
  short* obase = tmp + ((size_t)(b * F_ + f)) * T_ * H_;
#pragma unroll
  for (int mi = 0; mi < 4; ++mi) {
#pragma unroll
    for (int q = 0; q < 4; ++q) {
      int t = t0 + wm * 64 + mi * 16 + (lane >> 4) * 4 + q;
      if (t < T_) {
#pragma unroll
        for (int ni = 0; ni < 4; ++ni) {
          int h = wn * 64 + ni * 16 + (lane & 15);
          obase[(size_t)t * H_ + h] = f2bf(acc[mi][ni][q]);
        }
      }
    }
  }
}

// ---------------- final transpose: tmp[b,f,t,h] bf16 -> out[b,h,t,f] fp32
__global__ __launch_bounds__(256) void trans_kernel(const short* __restrict__ tmp,
                                                    float* __restrict__ out) {
  __shared__ float L[64][129];
  const int t = blockIdx.x;
  const int b = blockIdx.y;
  {
    const int h0 = (threadIdx.x & 15) * 8;
    const int fb = threadIdx.x >> 4;     // 0..15
#pragma unroll
    for (int i = 0; i < 4; ++i) {
      int f = fb + 16 * i;
      s16x8 v = *reinterpret_cast<const s16x8*>(
          &tmp[(((size_t)(b * F_ + f)) * T_ + t) * H_ + h0]);
#pragma unroll
      for (int u = 0; u < 8; ++u) L[f][h0 + u] = bf2f(v[u]);
    }
  }
  __syncthreads();
  {
    const int fo = threadIdx.x & 63;
    const int h0 = threadIdx.x >> 6;
#pragma unroll
    for (int i = 0; i < 32; ++i) {
      int h = h0 * 32 + i;
      out[(((size_t)(b * H_ + h)) * T_ + t) * F_ + fo] = L[fo][h];
    }
  }
}

// ---------------- fallback (exact fp32, slow)
__global__ __launch_bounds__(256) void naive_kernel(const float* __restrict__ x,
                                                    const float* __restrict__ W,
                                                    const int* __restrict__ idx,
                                                    float* __restrict__ out,
                                                    int jmax, size_t n) {
  size_t o = (size_t)blockIdx.x * 256 + threadIdx.x;
  if (o >= n) return;
  int f = (int)(o & 63);
  size_t r = o >> 6;
  int t = (int)(r % T_); r /= T_;
  int h = (int)(r % H_);
  int b = (int)(r / H_);
  float s = 0.0f;
  for (int c = 0; c < C_; ++c) {
    const float* xr = x + (((size_t)(b * C_ + c)) * T_ + t) * NF_;
    const float* wr = W + (((size_t)(f * H_ + h)) * C_ + c) * jmax;
    for (int j = 0; j < jmax; ++j) s += xr[idx[f * jmax + j]] * wr[j];
  }
  out[o] = s;
}

extern "C" void kernel_launch(void* const* d_in, const int* in_sizes, int n_in,
                              void* d_out, int out_size, void* d_ws, size_t ws_size,
                              hipStream_t stream) {
  const float* x  = (const float*)d_in[0];
  const float* W  = (const float*)d_in[1];
  const int* idx  = (const int*)d_in[2];
  float* out      = (float*)d_out;

  const int jmax = in_sizes[2] / F_;          // idx is (F_, jmax)
  const int JPAD = (jmax + 7) & ~7;

  const size_t xbytes = (size_t)B_ * T_ * NFP_ * C_ * 2;
  const size_t wbytes = (size_t)F_ * H_ * C_ * JPAD * 2;
  const size_t tbytes = (size_t)B_ * F_ * T_ * H_ * 2;   // bf16 tmp
  const size_t wwbytes = 256;
  const size_t lws = (size_t)8 * C_ * jmax * 2;

  if (JPAD <= 32 && ws_size >= xbytes + wbytes + tbytes + wwbytes && lws <= 48 * 1024) {
    short* xT   = (short*)d_ws;
    short* Wp   = (short*)((char*)d_ws + xbytes);
    short* tmp  = (short*)((char*)d_ws + xbytes + wbytes);
    int* wwidth = (int*)((char*)d_ws + xbytes + wbytes + tbytes);
    // wwidth is re-poisoned to 0xAAAAAAAA (negative) each call; wprep's
    // atomicMax(wwidth[f], width>=0) self-initializes it.

    hipLaunchKernelGGL(xprep_kernel, dim3(T_, B_), dim3(256), 0, stream, x, xT);
    hipLaunchKernelGGL(wprep_kernel, dim3(F_ * 16), dim3(256), lws, stream,
                       W, Wp, wwidth, jmax, JPAD);
    hipLaunchKernelGGL(gemm_kernel, dim3(1024), dim3(256), 0, stream,
                       xT, Wp, idx, wwidth, tmp, jmax, JPAD);
    hipLaunchKernelGGL(trans_kernel, dim3(T_, B_), dim3(256), 0, stream, tmp, out);
  } else {
    const size_t n = (size_t)B_ * H_ * T_ * F_;
    hipLaunchKernelGGL(naive_kernel, dim3((unsigned)((n + 255) / 256)), dim3(256), 0, stream,
                       x, W, idx, out, jmax, n);
  }
}